// Round 1
// baseline (1395.110 us; speedup 1.0000x reference)
//
#include <hip/hip_runtime.h>
#include <math.h>

#define B_ 8
#define C_ 768
#define H_ 128
#define W_ 128
#define NMASK 450
#define NKX 30
#define NKY 15
#define OMEGA 0.04908738521234052f  /* 2*pi/128 */

__device__ __forceinline__ float shrinkf(float v) {
    float a = fabsf(v) - 0.01f;
    a = a > 0.f ? a : 0.f;
    return copysignf(a, v);
}

// embT[c][n] = alpha[c] * FREQ_EMB[kx(n), ky(n), c]
__global__ void build_embT(const float* __restrict__ alpha, float* __restrict__ embT) {
    int idx = blockIdx.x * 256 + threadIdx.x;
    if (idx >= C_ * NMASK) return;
    int ch = idx / NMASK;
    int n  = idx - ch * NMASK;
    int kxi = n / NKY;
    int kyi = n - kxi * NKY;
    int kxv = (kxi < 15) ? (kxi + 2) : (kxi + 97);
    int kyv = kyi + 2;
    float val;
    if (ch < 384) {
        int j = ch >> 1;
        float dv = __expf((float)j * (-9.210340371976184f / 192.0f));
        float arg = (float)kxv * dv;
        val = (ch & 1) ? cosf(arg) : sinf(arg);
    } else {
        int cc = ch - 384;
        int j = cc >> 1;
        float dv = __expf((float)j * (-9.210340371976184f / 192.0f));
        float arg = (float)kyv * dv;
        val = (cc & 1) ? cosf(arg) : sinf(arg);
    }
    embT[idx] = alpha[ch] * val;
}

// Forward partial DFT per (b,c) image. Block=128 threads (thread = row h).
// Step A: T[h][ky] = sum_w x[h][w] e^{-i w ky w0}, rotation twiddles.
// Step B: X[kx][ky] = (1/128) sum_h T[h][ky] e^{-i h kx w0}, kx-conjugate-paired.
__global__ __launch_bounds__(128) void fwd_kernel(
    const float* __restrict__ x, const float* __restrict__ embT,
    float* __restrict__ XR, float* __restrict__ XI)
{
    __shared__ float Tr[H_][16];
    __shared__ float Ti[H_][16];
    int ch = blockIdx.x;
    int b  = blockIdx.y;
    int h  = threadIdx.x;

    const float4* xrow = (const float4*)(x + ((size_t)(b * C_ + ch) * H_ + h) * W_);

    float ar[NKY], ai[NKY], cs[NKY], sn[NKY], cd[NKY], sd[NKY];
    #pragma unroll
    for (int k = 0; k < NKY; ++k) {
        ar[k] = 0.f; ai[k] = 0.f; cs[k] = 1.f; sn[k] = 0.f;
        __sincosf(OMEGA * (float)(k + 2), &sd[k], &cd[k]);
    }
    #pragma unroll 1
    for (int w4 = 0; w4 < 32; ++w4) {
        float4 xv = xrow[w4];
        float xe[4] = {xv.x, xv.y, xv.z, xv.w};
        #pragma unroll
        for (int e = 0; e < 4; ++e) {
            float xval = xe[e];
            #pragma unroll
            for (int k = 0; k < NKY; ++k) {
                ar[k] = fmaf(xval, cs[k], ar[k]);
                ai[k] = fmaf(-xval, sn[k], ai[k]);
                float nc = cs[k] * cd[k] - sn[k] * sd[k];
                float ns = fmaf(cs[k], sd[k], sn[k] * cd[k]);
                cs[k] = nc; sn[k] = ns;
            }
        }
    }
    #pragma unroll
    for (int k = 0; k < NKY; ++k) { Tr[h][k] = ar[k]; Ti[h][k] = ai[k]; }
    __syncthreads();

    const float inv128 = 1.0f / 128.0f;
    size_t obase = (size_t)(b * C_ + ch) * NMASK;
    const float* embrow = embT + (size_t)ch * NMASK;
    // 225 conjugate pairs: (kxv, 128-kxv) share twiddles
    for (int p = threadIdx.x; p < 225; p += 128) {
        int kxp = p / NKY;
        int kyi = p - kxp * NKY;
        int kxv = kxp + 2;
        float cdv, sdv;
        __sincosf(OMEGA * (float)kxv, &sdv, &cdv);
        float c = 1.f, s = 0.f;
        float xrA = 0.f, xiA = 0.f, xrB = 0.f, xiB = 0.f;
        #pragma unroll 1
        for (int hh = 0; hh < H_; ++hh) {
            float tr = Tr[hh][kyi];
            float ti = Ti[hh][kyi];
            xrA += tr * c + ti * s;   // e^{-i}
            xiA += ti * c - tr * s;
            xrB += tr * c - ti * s;   // e^{+i} (mirror kx)
            xiB += ti * c + tr * s;
            float nc = c * cdv - s * sdv;
            float ns = fmaf(c, sdv, s * cdv);
            c = nc; s = ns;
        }
        int nA = kxp * NKY + kyi;
        int nB = (29 - kxp) * NKY + kyi;
        XR[obase + nA] = xrA * inv128 + embrow[nA];
        XI[obase + nA] = xiA * inv128;
        XR[obase + nB] = xrB * inv128 + embrow[nB];
        XI[obase + nB] = xiB * inv128;
    }
}

// One complex linear layer: out = in @ (Wr + iWi) + (Br +/- Bi), optional softshrink.
// Planar layout (B, C, NMASK). Block 256 = 64 n-lanes x 4 waves; wave owns 24 o's.
__global__ __launch_bounds__(256) void cmlp_kernel(
    const float* __restrict__ inR, const float* __restrict__ inI,
    const float* __restrict__ Wr, const float* __restrict__ Wi,
    const float* __restrict__ Br, const float* __restrict__ Bi,
    float* __restrict__ outR, float* __restrict__ outI, int do_shrink)
{
    int lane = threadIdx.x & 63;
    int wave = threadIdx.x >> 6;
    int n = blockIdx.x * 64 + lane;
    int k = blockIdx.y;
    int b = blockIdx.z;
    bool valid = (n < NMASK);
    int nc = valid ? n : 0;
    int o0 = wave * 24;

    float accR[24], accI[24];
    #pragma unroll
    for (int j = 0; j < 24; ++j) { accR[j] = 0.f; accI[j] = 0.f; }

    const float* baseR = inR + (size_t)(b * C_ + k * 96) * NMASK + nc;
    const float* baseI = inI + (size_t)(b * C_ + k * 96) * NMASK + nc;
    const float* wr0 = Wr + (size_t)k * 96 * 96 + o0;
    const float* wi0 = Wi + (size_t)k * 96 * 96 + o0;

    #pragma unroll 1
    for (int i = 0; i < 96; ++i) {
        float ar = baseR[(size_t)i * NMASK];
        float ai = baseI[(size_t)i * NMASK];
        if (!valid) { ar = 0.f; ai = 0.f; }
        const float* wr = wr0 + i * 96;
        const float* wi = wi0 + i * 96;
        #pragma unroll
        for (int j = 0; j < 24; ++j) {
            float wrv = wr[j];
            float wiv = wi[j];
            accR[j] = fmaf(ar, wrv, accR[j]);
            accR[j] = fmaf(-ai, wiv, accR[j]);
            accI[j] = fmaf(ai, wrv, accI[j]);
            accI[j] = fmaf(ar, wiv, accI[j]);
        }
    }
    #pragma unroll
    for (int j = 0; j < 24; ++j) {
        int o = o0 + j;
        float br = Br[k * 96 + o];
        float bi = Bi[k * 96 + o];
        float r  = accR[j] + br - bi;
        float im = accI[j] + br + bi;
        if (do_shrink) { r = shrinkf(r); im = shrinkf(im); }
        if (valid) {
            outR[(size_t)(b * C_ + k * 96 + o) * NMASK + n] = r;
            outI[(size_t)(b * C_ + k * 96 + o) * NMASK + n] = im;
        }
    }
}

// Inverse partial DFT per (b,c). Block=128 (thread = column w).
// Step C: U[kx][w] = (2/128) sum_ky X[kx][ky] e^{+i w ky w0}
// Step D: out[h][w] = sum over 15 conjugate kx-pairs of (UrA+UrB)cos - (UiA-UiB)sin
__global__ __launch_bounds__(128) void inv_kernel(
    const float* __restrict__ XR, const float* __restrict__ XI,
    float* __restrict__ out)
{
    __shared__ float Xr[NMASK], Xi[NMASK];
    __shared__ float Ur[NKX][128], Ui[NKX][128];
    __shared__ float ct[128], st[128];
    int ch = blockIdx.x;
    int b  = blockIdx.y;
    int tid = threadIdx.x;

    __sincosf(OMEGA * (float)tid, &st[tid], &ct[tid]);
    size_t ibase = (size_t)(b * C_ + ch) * NMASK;
    for (int i = tid; i < NMASK; i += 128) {
        Xr[i] = XR[ibase + i];
        Xi[i] = XI[ibase + i];
    }
    __syncthreads();

    const float scale = 2.0f / 128.0f;
    #pragma unroll 1
    for (int o = tid; o < NKX * 128; o += 128) {
        int kxi = o >> 7;
        int w = o & 127;
        float c = ct[(2 * w) & 127], s = st[(2 * w) & 127];
        float cdv = ct[w], sdv = st[w];
        float ur = 0.f, ui = 0.f;
        #pragma unroll
        for (int kyi = 0; kyi < NKY; ++kyi) {
            float xr = Xr[kxi * NKY + kyi];
            float xi = Xi[kxi * NKY + kyi];
            ur += xr * c - xi * s;   // e^{+i}
            ui += xr * s + xi * c;
            float ncv = c * cdv - s * sdv;
            float nsv = fmaf(c, sdv, s * cdv);
            c = ncv; s = nsv;
        }
        Ur[kxi][w] = ur * scale;
        Ui[kxi][w] = ui * scale;
    }
    __syncthreads();

    int w = tid;
    size_t obase = (size_t)(b * C_ + ch) * H_ * W_ + w;
    #pragma unroll 1
    for (int hc = 0; hc < 8; ++hc) {
        int h0 = hc * 16;
        float acc[16];
        #pragma unroll
        for (int t = 0; t < 16; ++t) acc[t] = 0.f;
        #pragma unroll 1
        for (int kxp = 0; kxp < 15; ++kxp) {
            int kxv = kxp + 2;
            float up = Ur[kxp][w] + Ur[29 - kxp][w];
            float um = Ui[kxp][w] - Ui[29 - kxp][w];
            int i0 = (kxv * h0) & 127;
            float c = ct[i0], s = st[i0];
            float cdv = ct[kxv], sdv = st[kxv];
            #pragma unroll
            for (int t = 0; t < 16; ++t) {
                acc[t] = fmaf(up, c, acc[t]);
                acc[t] = fmaf(-um, s, acc[t]);
                float ncv = c * cdv - s * sdv;
                float nsv = fmaf(c, sdv, s * cdv);
                c = ncv; s = nsv;
            }
        }
        #pragma unroll
        for (int t = 0; t < 16; ++t) {
            out[obase + (size_t)(h0 + t) * W_] = acc[t];
        }
    }
}

extern "C" void kernel_launch(void* const* d_in, const int* in_sizes, int n_in,
                              void* d_out, int out_size, void* d_ws, size_t ws_size,
                              hipStream_t stream)
{
    const float* x     = (const float*)d_in[0];
    const float* alpha = (const float*)d_in[1];
    const float* w1r   = (const float*)d_in[2];
    const float* b1r   = (const float*)d_in[3];
    const float* w1i   = (const float*)d_in[4];
    const float* b1i   = (const float*)d_in[5];
    const float* w2r   = (const float*)d_in[6];
    const float* b2r   = (const float*)d_in[7];
    const float* w2i   = (const float*)d_in[8];
    const float* b2i   = (const float*)d_in[9];
    float* outp = (float*)d_out;

    const size_t nBC = (size_t)B_ * C_ * NMASK;  // 2,764,800
    float* embT = (float*)d_ws;
    float* XR = embT + (size_t)C_ * NMASK;
    float* XI = XR + nBC;
    float* R1 = XI + nBC;
    float* I1 = R1 + nBC;

    build_embT<<<dim3((C_ * NMASK + 255) / 256), dim3(256), 0, stream>>>(alpha, embT);
    fwd_kernel<<<dim3(C_, B_), dim3(128), 0, stream>>>(x, embT, XR, XI);
    cmlp_kernel<<<dim3(8, 8, 8), dim3(256), 0, stream>>>(XR, XI, w1r, w1i, b1r, b1i, R1, I1, 0);
    cmlp_kernel<<<dim3(8, 8, 8), dim3(256), 0, stream>>>(R1, I1, w2r, w2i, b2r, b2i, XR, XI, 1);
    inv_kernel<<<dim3(C_, B_), dim3(128), 0, stream>>>(XR, XI, outp);
}